// Round 2
// baseline (2463.899 us; speedup 1.0000x reference)
//
#include <hip/hip_runtime.h>

// ChildSum TreeLSTM, complete 4-ary tree.
// N=65536 nodes, D=300 input, H=256 hidden, K=4 children.
// Levels (bottom-up): [21845,65536) [5461,21845) [1365,5461) [341,1365)
//                     [85,341) [21,85) [5,21) [1,5) [0,1)
// Leaves are exactly nodes >= 16384 (4*16384+1 > 65535).
// NOTE: reference applies ih_b / uh_b at leaves too (h_sum=0 but bias stays).
// Children of contiguous range [s,e) are contiguous [4s+1, 4e+1).

#define NTOT 65536
#define DD   300
#define HH   256
#define NB   8          // nodes per block
#define LEAF_START 16384

__device__ __forceinline__ float sigm(float x) { return 1.f / (1.f + __expf(-x)); }
__device__ __forceinline__ float ftanh(float x) {
    x = fminf(15.f, fmaxf(-15.f, x));
    float e = __expf(2.f * x);
    return (e - 1.f) / (e + 1.f);
}
__device__ __forceinline__ float dot4(float4 a, float4 b, float acc) {
    acc = fmaf(a.x, b.x, acc);
    acc = fmaf(a.y, b.y, acc);
    acc = fmaf(a.z, b.z, acc);
    acc = fmaf(a.w, b.w, acc);
    return acc;
}

// -------- leaf kernel: nodes with no children --------
// i = sigm(ix + ix_b + ih_b), u = tanh(ux + ux_b + uh_b); c = i*u; h = tanh(c)
__global__ __launch_bounds__(256) void leaf_kernel(
    const float* __restrict__ X,
    const float* __restrict__ ixw, const float* __restrict__ ixb,
    const float* __restrict__ ihb,
    const float* __restrict__ uxw, const float* __restrict__ uxb,
    const float* __restrict__ uhb,
    float* __restrict__ h, float* __restrict__ c,
    int s, int e)
{
    __shared__ float xs[NB][DD];
    const int base = s + blockIdx.x * NB;
    const int tid  = threadIdx.x;

    #pragma unroll
    for (int n = 0; n < NB; ++n) {
        const int g = base + n;
        if (g < e) {
            for (int d = tid; d < DD; d += 256) xs[n][d] = X[(size_t)g * DD + d];
        } else {
            for (int d = tid; d < DD; d += 256) xs[n][d] = 0.f;
        }
    }
    __syncthreads();

    const int j = tid;
    float aI[NB], aU[NB];
    #pragma unroll
    for (int n = 0; n < NB; ++n) { aI[n] = 0.f; aU[n] = 0.f; }

    const float* wi = ixw + (size_t)j * DD;
    const float* wu = uxw + (size_t)j * DD;
    for (int d = 0; d < DD; d += 4) {
        const float4 a = *(const float4*)(wi + d);
        const float4 b = *(const float4*)(wu + d);
        #pragma unroll
        for (int n = 0; n < NB; ++n) {
            const float4 x = *(const float4*)(&xs[n][d]);
            aI[n] = dot4(a, x, aI[n]);
            aU[n] = dot4(b, x, aU[n]);
        }
    }

    const float bi = ixb[j] + ihb[j];   // recurrent bias applies even with h_sum = 0
    const float bu = uxb[j] + uhb[j];
    #pragma unroll
    for (int n = 0; n < NB; ++n) {
        const int g = base + n;
        if (g >= e) break;
        const float iv = sigm(aI[n] + bi);
        const float uv = ftanh(aU[n] + bu);
        const float cn = iv * uv;
        h[(size_t)g * HH + j] = ftanh(cn);
        c[(size_t)g * HH + j] = cn;
    }
}

// -------- internal-level kernel: full gates + child gather --------
__global__ __launch_bounds__(256) void level_kernel(
    const float* __restrict__ X,
    const float* __restrict__ ixw, const float* __restrict__ ixb,
    const float* __restrict__ ihw, const float* __restrict__ ihb,
    const float* __restrict__ uxw, const float* __restrict__ uxb,
    const float* __restrict__ uhw, const float* __restrict__ uhb,
    const float* __restrict__ fiw, const float* __restrict__ fib,
    const float* __restrict__ fhw, const float* __restrict__ fhb,
    float* __restrict__ h, float* __restrict__ c,
    float* __restrict__ out,
    int s, int e)
{
    __shared__ float xs[NB][DD];        // 9.6 KB
    __shared__ float hs[4 * NB][HH];    // 32 KB  child h (0 if invalid child)
    __shared__ float hsum[NB][HH];      // 8 KB

    const int base  = s + blockIdx.x * NB;
    const int tid   = threadIdx.x;
    const int cbase = 4 * base + 1;     // first child of first node in block

    // stage x rows
    #pragma unroll
    for (int n = 0; n < NB; ++n) {
        const int g = base + n;
        if (g < e) {
            for (int d = tid; d < DD; d += 256) xs[n][d] = X[(size_t)g * DD + d];
        } else {
            for (int d = tid; d < DD; d += 256) xs[n][d] = 0.f;
        }
    }
    // stage child h (masked)
    for (int idx = tid; idx < 4 * NB * HH; idx += 256) {
        const int r = idx >> 8, col = idx & 255;
        const int cg = cbase + r;
        hs[r][col] = (cg < NTOT) ? h[(size_t)cg * HH + col] : 0.f;
    }
    __syncthreads();

    // h_sum per node
    #pragma unroll
    for (int n = 0; n < NB; ++n)
        hsum[n][tid] = hs[4*n][tid] + hs[4*n+1][tid] + hs[4*n+2][tid] + hs[4*n+3][tid];
    __syncthreads();

    const int j = tid;

    // ---- input projections (ix, ux, fi) ----
    float aI[NB], aU[NB], aF[NB];
    #pragma unroll
    for (int n = 0; n < NB; ++n) { aI[n] = 0.f; aU[n] = 0.f; aF[n] = 0.f; }
    {
        const float* wi = ixw + (size_t)j * DD;
        const float* wu = uxw + (size_t)j * DD;
        const float* wf = fiw + (size_t)j * DD;
        for (int d = 0; d < DD; d += 4) {
            const float4 a = *(const float4*)(wi + d);
            const float4 b = *(const float4*)(wu + d);
            const float4 f = *(const float4*)(wf + d);
            #pragma unroll
            for (int n = 0; n < NB; ++n) {
                const float4 x = *(const float4*)(&xs[n][d]);
                aI[n] = dot4(a, x, aI[n]);
                aU[n] = dot4(b, x, aU[n]);
                aF[n] = dot4(f, x, aF[n]);
            }
        }
    }

    // ---- recurrent matvecs (ih, uh on h_sum; fh per child) ----
    float aIH[NB], aUH[NB], aFH[4 * NB];
    #pragma unroll
    for (int n = 0; n < NB; ++n) { aIH[n] = 0.f; aUH[n] = 0.f; }
    #pragma unroll
    for (int r = 0; r < 4 * NB; ++r) aFH[r] = 0.f;
    {
        const float* wih = ihw + (size_t)j * HH;
        const float* wuh = uhw + (size_t)j * HH;
        const float* wfh = fhw + (size_t)j * HH;
        for (int t = 0; t < HH; t += 4) {
            const float4 a = *(const float4*)(wih + t);
            const float4 b = *(const float4*)(wuh + t);
            const float4 f = *(const float4*)(wfh + t);
            #pragma unroll
            for (int n = 0; n < NB; ++n) {
                const float4 hv = *(const float4*)(&hsum[n][t]);
                aIH[n] = dot4(a, hv, aIH[n]);
                aUH[n] = dot4(b, hv, aUH[n]);
            }
            #pragma unroll
            for (int r = 0; r < 4 * NB; ++r) {
                const float4 hv = *(const float4*)(&hs[r][t]);
                aFH[r] = dot4(f, hv, aFH[r]);
            }
        }
    }

    // ---- gates / state update ----
    const float bi = ixb[j] + ihb[j];
    const float bu = uxb[j] + uhb[j];
    const float bf = fib[j] + fhb[j];
    #pragma unroll
    for (int n = 0; n < NB; ++n) {
        const int g = base + n;
        if (g >= e) break;
        float fc = 0.f;
        #pragma unroll
        for (int k = 0; k < 4; ++k) {
            const int cg = cbase + 4 * n + k;
            const float cc = (cg < NTOT) ? c[(size_t)cg * HH + j] : 0.f;
            const float fg = sigm(aF[n] + bf + aFH[4 * n + k]);
            fc = fmaf(fg, cc, fc);
        }
        const float iv = sigm(aI[n] + bi + aIH[n]);
        const float uv = ftanh(aU[n] + bu + aUH[n]);
        const float cn = fmaf(iv, uv, fc);
        const float hn = ftanh(cn);
        h[(size_t)g * HH + j] = hn;
        c[(size_t)g * HH + j] = cn;
        if (g == 0) { out[j] = hn; out[HH + j] = cn; }
    }
}

extern "C" void kernel_launch(void* const* d_in, const int* in_sizes, int n_in,
                              void* d_out, int out_size, void* d_ws, size_t ws_size,
                              hipStream_t stream) {
    const float* X   = (const float*)d_in[0];
    const float* ixw = (const float*)d_in[1];
    const float* ixb = (const float*)d_in[2];
    const float* ihw = (const float*)d_in[3];
    const float* ihb = (const float*)d_in[4];
    const float* uxw = (const float*)d_in[5];
    const float* uxb = (const float*)d_in[6];
    const float* uhw = (const float*)d_in[7];
    const float* uhb = (const float*)d_in[8];
    const float* fiw = (const float*)d_in[9];
    const float* fib = (const float*)d_in[10];
    const float* fhw = (const float*)d_in[11];
    const float* fhb = (const float*)d_in[12];
    float* out = (float*)d_out;

    float* h = (float*)d_ws;                      // N*H floats
    float* c = h + (size_t)NTOT * HH;             // N*H floats (134 MB total)

    // ---- leaves (nodes >= 16384): two contiguous ranges ----
    {
        const int s0 = 21845, e0 = NTOT;
        const int nb0 = (e0 - s0 + NB - 1) / NB;
        leaf_kernel<<<nb0, 256, 0, stream>>>(X, ixw, ixb, ihb, uxw, uxb, uhb, h, c, s0, e0);
        const int s1 = LEAF_START, e1 = 21845;
        const int nb1 = (e1 - s1 + NB - 1) / NB;
        leaf_kernel<<<nb1, 256, 0, stream>>>(X, ixw, ixb, ihb, uxw, uxb, uhb, h, c, s1, e1);
    }

    // ---- internal levels bottom-up ----
    const int starts[8] = {5461, 1365, 341, 85, 21, 5, 1, 0};
    const int ends[8]   = {16384, 5461, 1365, 341, 85, 21, 5, 1};
    for (int l = 0; l < 8; ++l) {
        const int s = starts[l], e = ends[l];
        const int nb = (e - s + NB - 1) / NB;
        level_kernel<<<nb, 256, 0, stream>>>(X,
            ixw, ixb, ihw, ihb, uxw, uxb, uhw, uhb, fiw, fib, fhw, fhb,
            h, c, out, s, e);
    }
}

// Round 5
// 1607.472 us; speedup vs baseline: 1.5328x; 1.5328x over previous
//
#include <hip/hip_runtime.h>

// ChildSum TreeLSTM, complete 4-ary tree.
// N=65536, D=300 (pad->320), H=256, K=4.
// Leaves = nodes [16384, 65536). Children of [s,e) are [4s+1, 4e+1).
// Round 3 kernel, resubmit #2 after repeated broker/container infra failures:
// leaves via bf16 MFMA GEMM (fused gate epilogue); internal levels fp32.

#define NTOT 65536
#define DD   300
#define KP   320          // padded K for bf16 GEMM (multiple of 64)
#define HH   256
#define NB   8            // nodes per block (internal level kernel)
#define LEAF_START 16384

typedef unsigned short ushort_t;
typedef unsigned int uint_t;
typedef __attribute__((ext_vector_type(8))) short bf16x8;
typedef __attribute__((ext_vector_type(4))) float f32x4;

__device__ __forceinline__ float sigm(float x) { return 1.f / (1.f + __expf(-x)); }
__device__ __forceinline__ float ftanh(float x) {
    x = fminf(15.f, fmaxf(-15.f, x));
    float e = __expf(2.f * x);
    return (e - 1.f) / (e + 1.f);
}
__device__ __forceinline__ float dot4(float4 a, float4 b, float acc) {
    acc = fmaf(a.x, b.x, acc);
    acc = fmaf(a.y, b.y, acc);
    acc = fmaf(a.z, b.z, acc);
    acc = fmaf(a.w, b.w, acc);
    return acc;
}
__device__ __forceinline__ ushort_t f2bf(float f) {
    union { float f; uint_t u; } v; v.f = f;
    uint_t r = v.u + 0x7fffu + ((v.u >> 16) & 1u);   // round-to-nearest-even
    return (ushort_t)(r >> 16);
}

// ---- convert X [N][300] fp32 -> Xb [N][320] bf16 (zero-padded) ----
__global__ __launch_bounds__(256) void conv_x(const float* __restrict__ X,
                                              uint_t* __restrict__ Xb2) {
    const size_t total = (size_t)NTOT * (KP / 2);     // uint pairs
    for (size_t id = (size_t)blockIdx.x * 256 + threadIdx.x; id < total;
         id += (size_t)gridDim.x * 256) {
        const int node = (int)(id / (KP / 2));
        const int p    = (int)(id % (KP / 2));
        const int k    = p * 2;
        const float f0 = (k < DD)     ? X[(size_t)node * DD + k]     : 0.f;
        const float f1 = (k + 1 < DD) ? X[(size_t)node * DD + k + 1] : 0.f;
        Xb2[id] = (uint_t)f2bf(f0) | ((uint_t)f2bf(f1) << 16);
    }
}

// ---- convert stacked [ixw; uxw] (each [256][300]) -> Wb [512][320] bf16 ----
__global__ __launch_bounds__(256) void conv_w(const float* __restrict__ ixw,
                                              const float* __restrict__ uxw,
                                              uint_t* __restrict__ Wb2) {
    const int total = 512 * (KP / 2);
    for (int id = blockIdx.x * 256 + threadIdx.x; id < total;
         id += gridDim.x * 256) {
        const int row = id / (KP / 2);
        const int p   = id % (KP / 2);
        const int k   = p * 2;
        const float* src = (row < 256) ? (ixw + (size_t)row * DD)
                                       : (uxw + (size_t)(row - 256) * DD);
        const float f0 = (k < DD)     ? src[k]     : 0.f;
        const float f1 = (k + 1 < DD) ? src[k + 1] : 0.f;
        Wb2[id] = (uint_t)f2bf(f0) | ((uint_t)f2bf(f1) << 16);
    }
}

// ---- leaf GEMM: rows = leaf nodes, cols = 64 ix-channels + same 64 ux-channels ----
// block: 64 rows x (64+64) cols, K = 320 in 5 tiles of 64. 4 waves, 256 thr.
// Fused epilogue: c = sigm(aI+bi)*tanh(aU+bu); h = tanh(c).
__global__ __launch_bounds__(256) void leaf_gemm(
    const ushort_t* __restrict__ Xb, const ushort_t* __restrict__ Wb,
    const float* __restrict__ ixb, const float* __restrict__ ihb,
    const float* __restrict__ uxb, const float* __restrict__ uhb,
    float* __restrict__ h, float* __restrict__ c)
{
    __shared__ bf16x8 Ash[64 * 8];    // 8 KB  (64 rows x 8 granules of 8 bf16)
    __shared__ bf16x8 Bsh[128 * 8];   // 16 KB (64 ix rows + 64 ux rows)

    const int tid  = threadIdx.x;
    const int lane = tid & 63;
    const int w    = tid >> 6;        // wave 0..3
    const int m16  = lane & 15;
    const int q    = lane >> 4;       // quarter 0..3

    const int row0 = LEAF_START + blockIdx.x * 64;   // leaf node base
    const int n0   = blockIdx.y * 64;                // channel base (0..192)

    const bf16x8* __restrict__ Xv = (const bf16x8*)Xb;   // granule-indexed, 40/row
    const bf16x8* __restrict__ Wv = (const bf16x8*)Wb;

    f32x4 accI[4], accU[4];
    #pragma unroll
    for (int nf = 0; nf < 4; ++nf) { accI[nf] = (f32x4)0.f; accU[nf] = (f32x4)0.f; }

    const int ar = (w << 4) | m16;    // this lane's A row in tile

    for (int kt = 0; kt < 5; ++kt) {
        __syncthreads();
        // stage A: 512 granules
        #pragma unroll
        for (int i = 0; i < 2; ++i) {
            const int G = tid + i * 256;
            const int r = G >> 3, g = G & 7;
            Ash[(r << 3) | (g ^ (r & 7))] =
                Xv[(size_t)(row0 + r) * 40 + kt * 8 + g];
        }
        // stage B: 1024 granules (rows 0..63 -> ix chans n0+., 64..127 -> ux)
        #pragma unroll
        for (int i = 0; i < 4; ++i) {
            const int G = tid + i * 256;
            const int br = G >> 3, g = G & 7;
            const int nsrc = ((br >> 6) << 8) + n0 + (br & 63);
            Bsh[(br << 3) | (g ^ (br & 7))] =
                Wv[(size_t)nsrc * 40 + kt * 8 + g];
        }
        __syncthreads();

        #pragma unroll
        for (int ks = 0; ks < 2; ++ks) {
            const int kg = ks * 4 + q;
            const bf16x8 a = Ash[(ar << 3) | (kg ^ (ar & 7))];
            #pragma unroll
            for (int nf = 0; nf < 4; ++nf) {
                const int bri = nf * 16 + m16;
                const bf16x8 bI = Bsh[(bri << 3) | (kg ^ (bri & 7))];
                accI[nf] = __builtin_amdgcn_mfma_f32_16x16x32_bf16(a, bI, accI[nf], 0, 0, 0);
                const int bru = 64 + nf * 16 + m16;
                const bf16x8 bU = Bsh[(bru << 3) | (kg ^ (bru & 7))];
                accU[nf] = __builtin_amdgcn_mfma_f32_16x16x32_bf16(a, bU, accU[nf], 0, 0, 0);
            }
        }
    }

    // epilogue: C/D layout col = lane&15, row = 4*(lane>>4)+reg
    const int node0 = row0 + (w << 4) + (q << 2);
    #pragma unroll
    for (int nf = 0; nf < 4; ++nf) {
        const int col = n0 + (nf << 4) + m16;
        const float bi = ixb[col] + ihb[col];   // recurrent biases apply at leaves
        const float bu = uxb[col] + uhb[col];
        #pragma unroll
        for (int r = 0; r < 4; ++r) {
            const float ai = accI[nf][r] + bi;
            const float au = accU[nf][r] + bu;
            const float cn = sigm(ai) * ftanh(au);
            const size_t off = (size_t)(node0 + r) * HH + col;
            c[off] = cn;
            h[off] = ftanh(cn);
        }
    }
}

// -------- internal-level kernel: full gates + child gather (fp32) --------
__global__ __launch_bounds__(256) void level_kernel(
    const float* __restrict__ X,
    const float* __restrict__ ixw, const float* __restrict__ ixb,
    const float* __restrict__ ihw, const float* __restrict__ ihb,
    const float* __restrict__ uxw, const float* __restrict__ uxb,
    const float* __restrict__ uhw, const float* __restrict__ uhb,
    const float* __restrict__ fiw, const float* __restrict__ fib,
    const float* __restrict__ fhw, const float* __restrict__ fhb,
    float* __restrict__ h, float* __restrict__ c,
    float* __restrict__ out,
    int s, int e)
{
    __shared__ float xs[NB][DD];
    __shared__ float hs[4 * NB][HH];
    __shared__ float hsum[NB][HH];

    const int base  = s + blockIdx.x * NB;
    const int tid   = threadIdx.x;
    const int cbase = 4 * base + 1;

    #pragma unroll
    for (int n = 0; n < NB; ++n) {
        const int g = base + n;
        if (g < e) {
            for (int d = tid; d < DD; d += 256) xs[n][d] = X[(size_t)g * DD + d];
        } else {
            for (int d = tid; d < DD; d += 256) xs[n][d] = 0.f;
        }
    }
    for (int idx = tid; idx < 4 * NB * HH; idx += 256) {
        const int r = idx >> 8, col = idx & 255;
        const int cg = cbase + r;
        hs[r][col] = (cg < NTOT) ? h[(size_t)cg * HH + col] : 0.f;
    }
    __syncthreads();

    #pragma unroll
    for (int n = 0; n < NB; ++n)
        hsum[n][tid] = hs[4*n][tid] + hs[4*n+1][tid] + hs[4*n+2][tid] + hs[4*n+3][tid];
    __syncthreads();

    const int j = tid;

    float aI[NB], aU[NB], aF[NB];
    #pragma unroll
    for (int n = 0; n < NB; ++n) { aI[n] = 0.f; aU[n] = 0.f; aF[n] = 0.f; }
    {
        const float* wi = ixw + (size_t)j * DD;
        const float* wu = uxw + (size_t)j * DD;
        const float* wf = fiw + (size_t)j * DD;
        for (int d = 0; d < DD; d += 4) {
            const float4 a = *(const float4*)(wi + d);
            const float4 b = *(const float4*)(wu + d);
            const float4 f = *(const float4*)(wf + d);
            #pragma unroll
            for (int n = 0; n < NB; ++n) {
                const float4 x = *(const float4*)(&xs[n][d]);
                aI[n] = dot4(a, x, aI[n]);
                aU[n] = dot4(b, x, aU[n]);
                aF[n] = dot4(f, x, aF[n]);
            }
        }
    }

    float aIH[NB], aUH[NB], aFH[4 * NB];
    #pragma unroll
    for (int n = 0; n < NB; ++n) { aIH[n] = 0.f; aUH[n] = 0.f; }
    #pragma unroll
    for (int r = 0; r < 4 * NB; ++r) aFH[r] = 0.f;
    {
        const float* wih = ihw + (size_t)j * HH;
        const float* wuh = uhw + (size_t)j * HH;
        const float* wfh = fhw + (size_t)j * HH;
        for (int t = 0; t < HH; t += 4) {
            const float4 a = *(const float4*)(wih + t);
            const float4 b = *(const float4*)(wuh + t);
            const float4 f = *(const float4*)(wfh + t);
            #pragma unroll
            for (int n = 0; n < NB; ++n) {
                const float4 hv = *(const float4*)(&hsum[n][t]);
                aIH[n] = dot4(a, hv, aIH[n]);
                aUH[n] = dot4(b, hv, aUH[n]);
            }
            #pragma unroll
            for (int r = 0; r < 4 * NB; ++r) {
                const float4 hv = *(const float4*)(&hs[r][t]);
                aFH[r] = dot4(f, hv, aFH[r]);
            }
        }
    }

    const float bi = ixb[j] + ihb[j];
    const float bu = uxb[j] + uhb[j];
    const float bf = fib[j] + fhb[j];
    #pragma unroll
    for (int n = 0; n < NB; ++n) {
        const int g = base + n;
        if (g >= e) break;
        float fc = 0.f;
        #pragma unroll
        for (int k = 0; k < 4; ++k) {
            const int cg = cbase + 4 * n + k;
            const float cc = (cg < NTOT) ? c[(size_t)cg * HH + j] : 0.f;
            const float fg = sigm(aF[n] + bf + aFH[4 * n + k]);
            fc = fmaf(fg, cc, fc);
        }
        const float iv = sigm(aI[n] + bi + aIH[n]);
        const float uv = ftanh(aU[n] + bu + aUH[n]);
        const float cn = fmaf(iv, uv, fc);
        const float hn = ftanh(cn);
        h[(size_t)g * HH + j] = hn;
        c[(size_t)g * HH + j] = cn;
        if (g == 0) { out[j] = hn; out[HH + j] = cn; }
    }
}

extern "C" void kernel_launch(void* const* d_in, const int* in_sizes, int n_in,
                              void* d_out, int out_size, void* d_ws, size_t ws_size,
                              hipStream_t stream) {
    const float* X   = (const float*)d_in[0];
    const float* ixw = (const float*)d_in[1];
    const float* ixb = (const float*)d_in[2];
    const float* ihw = (const float*)d_in[3];
    const float* ihb = (const float*)d_in[4];
    const float* uxw = (const float*)d_in[5];
    const float* uxb = (const float*)d_in[6];
    const float* uhw = (const float*)d_in[7];
    const float* uhb = (const float*)d_in[8];
    const float* fiw = (const float*)d_in[9];
    const float* fib = (const float*)d_in[10];
    const float* fhw = (const float*)d_in[11];
    const float* fhb = (const float*)d_in[12];
    float* out = (float*)d_out;

    // ws layout
    float* h = (float*)d_ws;                              // N*H f32
    float* c = h + (size_t)NTOT * HH;                     // N*H f32
    ushort_t* Xb = (ushort_t*)(c + (size_t)NTOT * HH);    // N*KP bf16
    ushort_t* Wb = Xb + (size_t)NTOT * KP;                // 512*KP bf16

    // ---- conversions ----
    conv_x<<<2048, 256, 0, stream>>>(X, (uint_t*)Xb);
    conv_w<<<320, 256, 0, stream>>>(ixw, uxw, (uint_t*)Wb);

    // ---- leaves via MFMA GEMM: 49152 rows x (4x(64+64)) cols ----
    {
        dim3 grid(49152 / 64, 4);
        leaf_gemm<<<grid, 256, 0, stream>>>(Xb, Wb, ixb, ihb, uxb, uhb, h, c);
    }

    // ---- internal levels bottom-up (fp32) ----
    const int starts[8] = {5461, 1365, 341, 85, 21, 5, 1, 0};
    const int ends[8]   = {16384, 5461, 1365, 341, 85, 21, 5, 1};
    for (int l = 0; l < 8; ++l) {
        const int s = starts[l], e = ends[l];
        const int nb = (e - s + NB - 1) / NB;
        level_kernel<<<nb, 256, 0, stream>>>(X,
            ixw, ixb, ihw, ihb, uxw, uxb, uhw, uhb, fiw, fib, fhw, fhb,
            h, c, out, s, e);
    }
}

// Round 6
// 219.564 us; speedup vs baseline: 11.2218x; 7.3212x over previous
//
#include <hip/hip_runtime.h>

// ChildSum TreeLSTM, complete 4-ary tree. N=65536, D=300(->320), H=256, K=4.
// Leaves = [16384,65536). Children of [s,e) are contiguous [4s+1,4e+1).
// Round 6: everything matmul-shaped on bf16 MFMA.
//   phase 1: conv to bf16; leaf GEMM (fused gates); input-proj GEMM for all
//            internal nodes (ix|ux|fi stacked -> pre[16384][768]).
//   phase 2 per level: hsum -> rec_gemm (hsum x [ih;uh]^T  +  childH x fh^T)
//            -> gate kernel (f32 gates, writes h bf16 + c f32).
// h row 65536 is a zeroed pad row masking node 16383's invalid child 65536.

#define NTOT 65536
#define DD   300
#define KP   320
#define HH   256
#define LEAF_START 16384

typedef unsigned short u16;
typedef unsigned int   u32;
typedef __attribute__((ext_vector_type(8))) short bf16x8;
typedef __attribute__((ext_vector_type(4))) float f32x4;

// ---- ws layout (bytes) ----
#define OFF_HB    0ull                                   // [65537][256] bf16
#define OFF_C     33554944ull                            // [65537][256] f32
#define OFF_PRE   100664832ull                           // [16384][768] bf16
#define OFF_WXB   125830656ull                           // [768][320] bf16
#define OFF_WHB   126322176ull                           // [768][256] bf16
#define OFF_UNION 126715392ull
#define OFF_XB    (OFF_UNION)                            // [65536][320] bf16 (phase1)
#define OFF_PIU   (OFF_UNION)                            // [11008][512] bf16 (phase2)
#define OFF_PF    (OFF_UNION + 11272192ull)              // [43776][256] bf16
#define OFF_HSUM  (OFF_UNION + 33685504ull)              // [11008][256] bf16

__device__ __forceinline__ float sigm(float x) { return 1.f / (1.f + __expf(-x)); }
__device__ __forceinline__ float ftanh(float x) {
    x = fminf(15.f, fmaxf(-15.f, x));
    float e = __expf(2.f * x);
    return (e - 1.f) / (e + 1.f);
}
__device__ __forceinline__ u16 f2bf(float f) {
    union { float f; u32 u; } v; v.f = f;
    u32 r = v.u + 0x7fffu + ((v.u >> 16) & 1u);
    return (u16)(r >> 16);
}
__device__ __forceinline__ float bf2f(u16 b) {
    union { u32 u; float f; } v; v.u = ((u32)b) << 16;
    return v.f;
}

// ---- zero the pad row (node index 65536) of hb and c ----
__global__ __launch_bounds__(256) void zero_pad(u16* __restrict__ hb,
                                                float* __restrict__ c) {
    const int t = threadIdx.x;
    hb[(size_t)NTOT * HH + t] = 0;
    c [(size_t)NTOT * HH + t] = 0.f;
}

// ---- X [N][300] f32 -> Xb [N][320] bf16 ----
__global__ __launch_bounds__(256) void conv_x(const float* __restrict__ X,
                                              u32* __restrict__ Xb2) {
    const size_t total = (size_t)NTOT * (KP / 2);
    for (size_t id = (size_t)blockIdx.x * 256 + threadIdx.x; id < total;
         id += (size_t)gridDim.x * 256) {
        const int node = (int)(id / (KP / 2));
        const int k    = ((int)(id % (KP / 2))) * 2;
        const float f0 = (k < DD)     ? X[(size_t)node * DD + k]     : 0.f;
        const float f1 = (k + 1 < DD) ? X[(size_t)node * DD + k + 1] : 0.f;
        Xb2[id] = (u32)f2bf(f0) | ((u32)f2bf(f1) << 16);
    }
}

// ---- stack [ixw; uxw; fiw] -> Wxb [768][320] bf16 ----
__global__ __launch_bounds__(256) void conv_wx(const float* __restrict__ ixw,
                                               const float* __restrict__ uxw,
                                               const float* __restrict__ fiw,
                                               u32* __restrict__ W2) {
    const int total = 768 * (KP / 2);
    for (int id = blockIdx.x * 256 + threadIdx.x; id < total;
         id += gridDim.x * 256) {
        const int row = id / (KP / 2);
        const int k   = (id % (KP / 2)) * 2;
        const float* src = (row < 256) ? (ixw + (size_t)row * DD)
                         : (row < 512) ? (uxw + (size_t)(row - 256) * DD)
                                       : (fiw + (size_t)(row - 512) * DD);
        const float f0 = (k < DD)     ? src[k]     : 0.f;
        const float f1 = (k + 1 < DD) ? src[k + 1] : 0.f;
        W2[id] = (u32)f2bf(f0) | ((u32)f2bf(f1) << 16);
    }
}

// ---- stack [ihw; uhw; fhw] -> Whb [768][256] bf16 ----
__global__ __launch_bounds__(256) void conv_wh(const float* __restrict__ ihw,
                                               const float* __restrict__ uhw,
                                               const float* __restrict__ fhw,
                                               u32* __restrict__ W2) {
    const int total = 768 * (HH / 2);
    for (int id = blockIdx.x * 256 + threadIdx.x; id < total;
         id += gridDim.x * 256) {
        const int row = id / (HH / 2);
        const int k   = (id % (HH / 2)) * 2;
        const float* src = (row < 256) ? (ihw + (size_t)row * HH)
                         : (row < 512) ? (uhw + (size_t)(row - 256) * HH)
                                       : (fhw + (size_t)(row - 512) * HH);
        W2[id] = (u32)f2bf(src[k]) | ((u32)f2bf(src[k + 1]) << 16);
    }
}

// ---- leaf GEMM: [49152 x 320] x [320 x (64ix+64ux)] per block, fused gates ----
__global__ __launch_bounds__(256) void leaf_gemm(
    const u16* __restrict__ Xb, const u16* __restrict__ Wxb,
    const float* __restrict__ ixb, const float* __restrict__ ihb,
    const float* __restrict__ uxb, const float* __restrict__ uhb,
    u16* __restrict__ hb, float* __restrict__ c)
{
    __shared__ bf16x8 Ash[64 * 8];
    __shared__ bf16x8 Bsh[128 * 8];

    const int tid  = threadIdx.x;
    const int lane = tid & 63;
    const int w    = tid >> 6;
    const int m16  = lane & 15;
    const int q    = lane >> 4;

    const int row0 = LEAF_START + blockIdx.x * 64;
    const int n0   = blockIdx.y * 64;

    const bf16x8* __restrict__ Xv = (const bf16x8*)Xb;   // 40 granules/row
    const bf16x8* __restrict__ Wv = (const bf16x8*)Wxb;

    f32x4 accI[4], accU[4];
    #pragma unroll
    for (int nf = 0; nf < 4; ++nf) { accI[nf] = (f32x4)0.f; accU[nf] = (f32x4)0.f; }

    const int ar = (w << 4) | m16;

    for (int kt = 0; kt < 5; ++kt) {
        __syncthreads();
        #pragma unroll
        for (int i = 0; i < 2; ++i) {
            const int G = tid + i * 256;
            const int r = G >> 3, g = G & 7;
            Ash[(r << 3) | (g ^ (r & 7))] = Xv[(size_t)(row0 + r) * 40 + kt * 8 + g];
        }
        #pragma unroll
        for (int i = 0; i < 4; ++i) {
            const int G = tid + i * 256;
            const int br = G >> 3, g = G & 7;
            const int nsrc = ((br >> 6) << 8) + n0 + (br & 63);
            Bsh[(br << 3) | (g ^ (br & 7))] = Wv[(size_t)nsrc * 40 + kt * 8 + g];
        }
        __syncthreads();

        #pragma unroll
        for (int ks = 0; ks < 2; ++ks) {
            const int kg = ks * 4 + q;
            const bf16x8 a = Ash[(ar << 3) | (kg ^ (ar & 7))];
            #pragma unroll
            for (int nf = 0; nf < 4; ++nf) {
                const int bri = nf * 16 + m16;
                const bf16x8 bI = Bsh[(bri << 3) | (kg ^ (bri & 7))];
                accI[nf] = __builtin_amdgcn_mfma_f32_16x16x32_bf16(a, bI, accI[nf], 0, 0, 0);
                const int bru = 64 + nf * 16 + m16;
                const bf16x8 bU = Bsh[(bru << 3) | (kg ^ (bru & 7))];
                accU[nf] = __builtin_amdgcn_mfma_f32_16x16x32_bf16(a, bU, accU[nf], 0, 0, 0);
            }
        }
    }

    const int node0 = row0 + (w << 4) + (q << 2);
    #pragma unroll
    for (int nf = 0; nf < 4; ++nf) {
        const int col = n0 + (nf << 4) + m16;
        const float bi = ixb[col] + ihb[col];
        const float bu = uxb[col] + uhb[col];
        #pragma unroll
        for (int r = 0; r < 4; ++r) {
            const float cn = sigm(accI[nf][r] + bi) * ftanh(accU[nf][r] + bu);
            const size_t off = (size_t)(node0 + r) * HH + col;
            c [off] = cn;
            hb[off] = f2bf(ftanh(cn));
        }
    }
}

// ---- input-proj GEMM for internal nodes: [16384 x 320] x [320 x 768] -> pre ----
__global__ __launch_bounds__(256) void proj_gemm(const u16* __restrict__ Xb,
                                                 const u16* __restrict__ Wxb,
                                                 u16* __restrict__ pre)
{
    __shared__ bf16x8 Ash[64 * 8];
    __shared__ bf16x8 Bsh[128 * 8];

    const int tid  = threadIdx.x;
    const int lane = tid & 63;
    const int w    = tid >> 6;
    const int m16  = lane & 15;
    const int q    = lane >> 4;

    const int row0 = blockIdx.x * 64;     // node 0..16383
    const int n0   = blockIdx.y * 128;    // col block of 768

    const bf16x8* __restrict__ Xv = (const bf16x8*)Xb;
    const bf16x8* __restrict__ Wv = (const bf16x8*)Wxb;

    f32x4 acc[8];
    #pragma unroll
    for (int nf = 0; nf < 8; ++nf) acc[nf] = (f32x4)0.f;

    const int ar = (w << 4) | m16;

    for (int kt = 0; kt < 5; ++kt) {
        __syncthreads();
        #pragma unroll
        for (int i = 0; i < 2; ++i) {
            const int G = tid + i * 256;
            const int r = G >> 3, g = G & 7;
            Ash[(r << 3) | (g ^ (r & 7))] = Xv[(size_t)(row0 + r) * 40 + kt * 8 + g];
        }
        #pragma unroll
        for (int i = 0; i < 4; ++i) {
            const int G = tid + i * 256;
            const int br = G >> 3, g = G & 7;
            Bsh[(br << 3) | (g ^ (br & 7))] = Wv[(size_t)(n0 + br) * 40 + kt * 8 + g];
        }
        __syncthreads();

        #pragma unroll
        for (int ks = 0; ks < 2; ++ks) {
            const int kg = ks * 4 + q;
            const bf16x8 a = Ash[(ar << 3) | (kg ^ (ar & 7))];
            #pragma unroll
            for (int nf = 0; nf < 8; ++nf) {
                const int bri = nf * 16 + m16;
                const bf16x8 b = Bsh[(bri << 3) | (kg ^ (bri & 7))];
                acc[nf] = __builtin_amdgcn_mfma_f32_16x16x32_bf16(a, b, acc[nf], 0, 0, 0);
            }
        }
    }

    const int node0 = row0 + (w << 4) + (q << 2);
    #pragma unroll
    for (int nf = 0; nf < 8; ++nf) {
        const int col = n0 + (nf << 4) + m16;
        #pragma unroll
        for (int r = 0; r < 4; ++r)
            pre[(size_t)(node0 + r) * 768 + col] = f2bf(acc[nf][r]);
    }
}

// ---- per-level: hsum (bf16) ----
__global__ __launch_bounds__(256) void hsum_kernel(const u16* __restrict__ hb,
                                                   u16* __restrict__ hsumb,
                                                   int crow0, int L)
{
    const int id = blockIdx.x * 256 + threadIdx.x;
    if (id >= L * 64) return;
    const int nloc = id >> 6;
    const int cu   = (id & 63) << 1;       // u32 pair index within row (0..126 step2)
    const u32* __restrict__ src = (const u32*)hb;
    float s0 = 0.f, s1 = 0.f, s2 = 0.f, s3 = 0.f;
    #pragma unroll
    for (int k = 0; k < 4; ++k) {
        const size_t ro = (size_t)(crow0 + 4 * nloc + k) * (HH / 2) + cu;
        const u32 a = src[ro], b = src[ro + 1];
        s0 += bf2f((u16)(a & 0xffff)); s1 += bf2f((u16)(a >> 16));
        s2 += bf2f((u16)(b & 0xffff)); s3 += bf2f((u16)(b >> 16));
    }
    u32* __restrict__ dst = (u32*)hsumb;
    const size_t oo = (size_t)nloc * (HH / 2) + cu;
    dst[oo]     = (u32)f2bf(s0) | ((u32)f2bf(s1) << 16);
    dst[oo + 1] = (u32)f2bf(s2) | ((u32)f2bf(s3) << 16);
}

// ---- per-level recurrent GEMM (two segments in one kernel) ----
// seg IU: hsumb[L x 256] x Whb[rows 0..511]^T   -> projIU [L][512]
// seg F :    hb[4L x 256] x Whb[rows 512..767]^T -> projF  [4L][256]
__global__ __launch_bounds__(256) void rec_gemm(const u16* __restrict__ hb,
                                                const u16* __restrict__ hsumb,
                                                const u16* __restrict__ Whb,
                                                u16* __restrict__ projIU,
                                                u16* __restrict__ projF,
                                                int crow0, int L)
{
    __shared__ bf16x8 Ash[64 * 8];
    __shared__ bf16x8 Bsh[128 * 8];

    const int nIUrb = (L + 63) >> 6;
    const int bid   = blockIdx.x;

    const u16* Aptr; u16* out;
    int ostride, Brow0, orow0, ocol0;
    if (bid < nIUrb * 4) {
        const int rb = bid >> 2, cb = bid & 3;
        Aptr = hsumb + (size_t)rb * 64 * HH;
        out = projIU; ostride = 512; orow0 = rb * 64;
        ocol0 = cb * 128; Brow0 = cb * 128;
    } else {
        const int b2 = bid - nIUrb * 4;
        const int rb = b2 >> 1, cb = b2 & 1;
        Aptr = hb + (size_t)(crow0 + rb * 64) * HH;
        out = projF; ostride = 256; orow0 = rb * 64;
        ocol0 = cb * 128; Brow0 = 512 + cb * 128;
    }

    const int tid  = threadIdx.x;
    const int lane = tid & 63;
    const int w    = tid >> 6;
    const int m16  = lane & 15;
    const int q    = lane >> 4;

    const bf16x8* __restrict__ Av = (const bf16x8*)Aptr;  // 32 granules/row
    const bf16x8* __restrict__ Wv = (const bf16x8*)Whb;

    f32x4 acc[8];
    #pragma unroll
    for (int nf = 0; nf < 8; ++nf) acc[nf] = (f32x4)0.f;

    const int ar = (w << 4) | m16;

    for (int kt = 0; kt < 4; ++kt) {
        __syncthreads();
        #pragma unroll
        for (int i = 0; i < 2; ++i) {
            const int G = tid + i * 256;
            const int r = G >> 3, g = G & 7;
            Ash[(r << 3) | (g ^ (r & 7))] = Av[(size_t)r * 32 + kt * 8 + g];
        }
        #pragma unroll
        for (int i = 0; i < 4; ++i) {
            const int G = tid + i * 256;
            const int br = G >> 3, g = G & 7;
            Bsh[(br << 3) | (g ^ (br & 7))] = Wv[(size_t)(Brow0 + br) * 32 + kt * 8 + g];
        }
        __syncthreads();

        #pragma unroll
        for (int ks = 0; ks < 2; ++ks) {
            const int kg = ks * 4 + q;
            const bf16x8 a = Ash[(ar << 3) | (kg ^ (ar & 7))];
            #pragma unroll
            for (int nf = 0; nf < 8; ++nf) {
                const int bri = nf * 16 + m16;
                const bf16x8 b = Bsh[(bri << 3) | (kg ^ (bri & 7))];
                acc[nf] = __builtin_amdgcn_mfma_f32_16x16x32_bf16(a, b, acc[nf], 0, 0, 0);
            }
        }
    }

    const int r0 = orow0 + (w << 4) + (q << 2);
    #pragma unroll
    for (int nf = 0; nf < 8; ++nf) {
        const int col = ocol0 + (nf << 4) + m16;
        #pragma unroll
        for (int r = 0; r < 4; ++r)
            out[(size_t)(r0 + r) * ostride + col] = f2bf(acc[nf][r]);
    }
}

// ---- per-level gates (f32 math) ----
__global__ __launch_bounds__(256) void gate_kernel(
    const u16* __restrict__ pre, const u16* __restrict__ projIU,
    const u16* __restrict__ projF,
    const float* __restrict__ ixb, const float* __restrict__ ihb,
    const float* __restrict__ uxb, const float* __restrict__ uhb,
    const float* __restrict__ fib, const float* __restrict__ fhb,
    u16* __restrict__ hb, float* __restrict__ c, float* __restrict__ out,
    int s, int crow0)
{
    const int nloc = blockIdx.x;
    const int j    = threadIdx.x;
    const int n    = s + nloc;

    const float aI = bf2f(pre[(size_t)n * 768 + j]) + ixb[j] + ihb[j]
                   + bf2f(projIU[(size_t)nloc * 512 + j]);
    const float aU = bf2f(pre[(size_t)n * 768 + 256 + j]) + uxb[j] + uhb[j]
                   + bf2f(projIU[(size_t)nloc * 512 + 256 + j]);
    const float fpre = bf2f(pre[(size_t)n * 768 + 512 + j]) + fib[j] + fhb[j];

    float fc = 0.f;
    #pragma unroll
    for (int k = 0; k < 4; ++k) {
        const float fg = sigm(fpre + bf2f(projF[(size_t)(4 * nloc + k) * 256 + j]));
        fc = fmaf(fg, c[(size_t)(crow0 + 4 * nloc + k) * HH + j], fc);
    }
    const float cn = fmaf(sigm(aI), ftanh(aU), fc);
    const float hn = ftanh(cn);
    hb[(size_t)n * HH + j] = f2bf(hn);
    c [(size_t)n * HH + j] = cn;
    if (n == 0) { out[j] = hn; out[HH + j] = cn; }
}

extern "C" void kernel_launch(void* const* d_in, const int* in_sizes, int n_in,
                              void* d_out, int out_size, void* d_ws, size_t ws_size,
                              hipStream_t stream) {
    const float* X   = (const float*)d_in[0];
    const float* ixw = (const float*)d_in[1];
    const float* ixb = (const float*)d_in[2];
    const float* ihw = (const float*)d_in[3];
    const float* ihb = (const float*)d_in[4];
    const float* uxw = (const float*)d_in[5];
    const float* uxb = (const float*)d_in[6];
    const float* uhw = (const float*)d_in[7];
    const float* uhb = (const float*)d_in[8];
    const float* fiw = (const float*)d_in[9];
    const float* fib = (const float*)d_in[10];
    const float* fhw = (const float*)d_in[11];
    const float* fhb = (const float*)d_in[12];
    float* out = (float*)d_out;

    char* ws = (char*)d_ws;
    u16*   hb    = (u16*)(ws + OFF_HB);
    float* cbuf  = (float*)(ws + OFF_C);
    u16*   pre   = (u16*)(ws + OFF_PRE);
    u16*   Wxb   = (u16*)(ws + OFF_WXB);
    u16*   Whb   = (u16*)(ws + OFF_WHB);
    u16*   Xb    = (u16*)(ws + OFF_XB);
    u16*   pIU   = (u16*)(ws + OFF_PIU);
    u16*   pF    = (u16*)(ws + OFF_PF);
    u16*   hsumb = (u16*)(ws + OFF_HSUM);

    zero_pad<<<1, 256, 0, stream>>>(hb, cbuf);
    conv_x <<<2048, 256, 0, stream>>>(X, (u32*)Xb);
    conv_wx<<<480, 256, 0, stream>>>(ixw, uxw, fiw, (u32*)Wxb);
    conv_wh<<<384, 256, 0, stream>>>(ihw, uhw, fhw, (u32*)Whb);

    leaf_gemm<<<dim3(768, 4), 256, 0, stream>>>(Xb, Wxb, ixb, ihb, uxb, uhb, hb, cbuf);
    proj_gemm<<<dim3(256, 6), 256, 0, stream>>>(Xb, Wxb, pre);

    const int starts[8] = {5461, 1365, 341, 85, 21, 5, 1, 0};
    const int ends[8]   = {16384, 5461, 1365, 341, 85, 21, 5, 1};
    for (int l = 0; l < 8; ++l) {
        const int s = starts[l], e = ends[l];
        const int L = e - s;
        const int crow0 = 4 * s + 1;
        const int nIUrb = (L + 63) >> 6;
        const int nFrb  = (4 * L + 63) >> 6;
        hsum_kernel<<<(L * 64 + 255) / 256, 256, 0, stream>>>(hb, hsumb, crow0, L);
        rec_gemm<<<nIUrb * 4 + nFrb * 2, 256, 0, stream>>>(hb, hsumb, Whb, pIU, pF, crow0, L);
        gate_kernel<<<L, 256, 0, stream>>>(pre, pIU, pF,
            ixb, ihb, uxb, uhb, fib, fhb, hb, cbuf, out, s, crow0);
    }
}